// Round 1
// baseline (397.467 us; speedup 1.0000x reference)
//
#include <hip/hip_runtime.h>

typedef unsigned short u16;
typedef unsigned int u32;

typedef __attribute__((ext_vector_type(8))) short bf16x8;
typedef __attribute__((ext_vector_type(4))) float f32x4;

static __device__ __forceinline__ u16 f2bf(float f) {
    u32 u = __float_as_uint(f);
    u32 r = (u + 0x7FFFu + ((u >> 16) & 1u)) >> 16;
    return (u16)r;
}
static __device__ __forceinline__ float bf2f(u16 h) {
    return __uint_as_float(((u32)h) << 16);
}

// ---------------- fp32 -> bf16 convert (vectorized) ----------------
__global__ __launch_bounds__(256) void convert_bf16_kernel(const float* __restrict__ x,
                                                           u16* __restrict__ y, int n4) {
    int i = blockIdx.x * 256 + threadIdx.x;
    if (i < n4) {
        float4 v = ((const float4*)x)[i];
        ushort4 o;
        o.x = f2bf(v.x); o.y = f2bf(v.y); o.z = f2bf(v.z); o.w = f2bf(v.w);
        ((ushort4*)y)[i] = o;
    }
}

// ---------------- W [K,N] fp32 -> W^T [N,K] bf16 ----------------
__global__ __launch_bounds__(256) void transpose_to_bf16_kernel(const float* __restrict__ W,
                                                                u16* __restrict__ WT, int D) {
    __shared__ float t[32][33];
    int bx = blockIdx.x, by = blockIdx.y;
    int tx = threadIdx.x, ty = threadIdx.y;
#pragma unroll
    for (int i = ty; i < 32; i += 8)
        t[i][tx] = W[(long)(by * 32 + i) * D + bx * 32 + tx];
    __syncthreads();
#pragma unroll
    for (int i = ty; i < 32; i += 8)
        WT[(long)(bx * 32 + i) * D + by * 32 + tx] = f2bf(t[tx][i]);
}

// ---------------- generic bf16 MFMA GEMM: C[m,n] = scale * sum_k A[m,k]*B[n,k] (+bias)(+mask) --------
// A: [M,K] bf16 row-major (lda), B: [N,K] bf16 row-major (ldb). Tile 128x128, BK=64.
// bias_mode: 0 none, 1 bias[col] (per-n), 2 bias[row] (per-m). madd: fp32 [M x mask_ld] added post-scale.
// c_bf16: 1 -> write u16 bf16, 0 -> write fp32.
__global__ __launch_bounds__(256) void gemm_bt_kernel(
    const u16* __restrict__ A, int lda, long sA,
    const u16* __restrict__ B, int ldb, long sB,
    void* __restrict__ C, int ldc, long sC, int c_bf16,
    const float* __restrict__ bias, int bias_mode,
    const float* __restrict__ madd, int mask_ld,
    float scale, int K) {
    __shared__ __align__(16) u16 As[128 * 64];
    __shared__ __align__(16) u16 Bs[128 * 64];
    const int b = blockIdx.z;
    const u16* Ab = A + (long)b * sA;
    const u16* Bb = B + (long)b * sB;
    const int tm = blockIdx.y * 128, tn = blockIdx.x * 128;
    const int tid = threadIdx.x, wave = tid >> 6, lane = tid & 63;
    const int wm = (wave >> 1) * 64, wn = (wave & 1) * 64;
    const int lr = lane >> 3, lc = lane & 7;   // staging: row-in-group, 16B-chunk
    const int fm = lane & 15, fq = lane >> 4;  // fragment: m/n index, quad

    f32x4 acc[4][4];
#pragma unroll
    for (int i = 0; i < 4; i++)
#pragma unroll
        for (int j = 0; j < 4; j++) acc[i][j] = (f32x4){0.f, 0.f, 0.f, 0.f};

    for (int k0 = 0; k0 < K; k0 += 64) {
        if (k0) __syncthreads();
#pragma unroll
        for (int i = 0; i < 4; i++) {
            int row = i * 32 + wave * 8;
            const u16* ga = Ab + (long)(tm + row + lr) * lda + k0 + lc * 8;
            const u16* gb = Bb + (long)(tn + row + lr) * ldb + k0 + lc * 8;
            __builtin_amdgcn_global_load_lds((const __attribute__((address_space(1))) void*)ga,
                                             (__attribute__((address_space(3))) void*)&As[row * 64],
                                             16, 0, 0);
            __builtin_amdgcn_global_load_lds((const __attribute__((address_space(1))) void*)gb,
                                             (__attribute__((address_space(3))) void*)&Bs[row * 64],
                                             16, 0, 0);
        }
        __syncthreads();
#pragma unroll
        for (int ks = 0; ks < 2; ks++) {
            bf16x8 af[4], bfr[4];
#pragma unroll
            for (int i = 0; i < 4; i++)
                af[i] = *(const bf16x8*)&As[(wm + i * 16 + fm) * 64 + ks * 32 + fq * 8];
#pragma unroll
            for (int j = 0; j < 4; j++)
                bfr[j] = *(const bf16x8*)&Bs[(wn + j * 16 + fm) * 64 + ks * 32 + fq * 8];
#pragma unroll
            for (int i = 0; i < 4; i++)
#pragma unroll
                for (int j = 0; j < 4; j++)
                    acc[i][j] = __builtin_amdgcn_mfma_f32_16x16x32_bf16(af[i], bfr[j], acc[i][j], 0, 0, 0);
        }
    }

#pragma unroll
    for (int i = 0; i < 4; i++) {
#pragma unroll
        for (int j = 0; j < 4; j++) {
#pragma unroll
            for (int r = 0; r < 4; r++) {
                int row = tm + wm + i * 16 + fq * 4 + r;
                int col = tn + wn + j * 16 + fm;
                float v = acc[i][j][r] * scale;
                if (bias_mode == 1) v += bias[col];
                else if (bias_mode == 2) v += bias[row];
                if (madd) v += madd[(long)row * mask_ld + col];
                if (c_bf16)
                    ((u16*)C)[(long)b * sC + (long)row * ldc + col] = f2bf(v);
                else
                    ((float*)C)[(long)b * sC + (long)row * ldc + col] = v;
            }
        }
    }
}

// ---------------- in-place row softmax over 2048 bf16 cols ----------------
__global__ __launch_bounds__(256) void softmax_kernel(u16* __restrict__ s) {
    const long row = blockIdx.x;
    u16* p = s + row * 2048;
    const int tid = threadIdx.x;
    const int lane = tid & 63, wave = tid >> 6;
    __shared__ float redm[4], reds[4];

    uint4 raw = ((const uint4*)p)[tid];
    float v[8];
    v[0] = bf2f(raw.x & 0xffff); v[1] = bf2f(raw.x >> 16);
    v[2] = bf2f(raw.y & 0xffff); v[3] = bf2f(raw.y >> 16);
    v[4] = bf2f(raw.z & 0xffff); v[5] = bf2f(raw.z >> 16);
    v[6] = bf2f(raw.w & 0xffff); v[7] = bf2f(raw.w >> 16);

    float m = v[0];
#pragma unroll
    for (int k = 1; k < 8; k++) m = fmaxf(m, v[k]);
#pragma unroll
    for (int off = 32; off; off >>= 1) m = fmaxf(m, __shfl_xor(m, off));
    if (lane == 0) redm[wave] = m;
    __syncthreads();
    m = fmaxf(fmaxf(redm[0], redm[1]), fmaxf(redm[2], redm[3]));

    float sum = 0.f;
#pragma unroll
    for (int k = 0; k < 8; k++) { v[k] = __expf(v[k] - m); sum += v[k]; }
#pragma unroll
    for (int off = 32; off; off >>= 1) sum += __shfl_xor(sum, off);
    if (lane == 0) reds[wave] = sum;
    __syncthreads();
    sum = reds[0] + reds[1] + reds[2] + reds[3];
    float inv = 1.f / sum;

    uint4 o;
    o.x = (u32)f2bf(v[0] * inv) | ((u32)f2bf(v[1] * inv) << 16);
    o.y = (u32)f2bf(v[2] * inv) | ((u32)f2bf(v[3] * inv) << 16);
    o.z = (u32)f2bf(v[4] * inv) | ((u32)f2bf(v[5] * inv) << 16);
    o.w = (u32)f2bf(v[6] * inv) | ((u32)f2bf(v[7] * inv) << 16);
    ((uint4*)p)[tid] = o;
}

extern "C" void kernel_launch(void* const* d_in, const int* in_sizes, int n_in,
                              void* d_out, int out_size, void* d_ws, size_t ws_size,
                              hipStream_t stream) {
    const float* x    = (const float*)d_in[0];
    const float* mask = (const float*)d_in[1];
    const float* Wq   = (const float*)d_in[2];
    const float* bq   = (const float*)d_in[3];
    const float* Wk   = (const float*)d_in[4];
    const float* bk   = (const float*)d_in[5];
    const float* Wv   = (const float*)d_in[6];
    const float* bv   = (const float*)d_in[7];
    float* out = (float*)d_out;

    const int B = 4, S = 2048, D = 1024;
    const long MS = (long)B * S;  // 8192

    size_t need = (size_t)(MS * D * 2) * 4 /* xb,Q,K,VT */
                + (size_t)(D * D * 2) * 3 /* W^T */
                + (size_t)B * S * S * 2;  /* scores */
    if (ws_size < need) return;  // workspace too small: fail cleanly

    char* ws = (char*)d_ws;
    u16* xb  = (u16*)ws; ws += (long)MS * D * 2;
    u16* wqt = (u16*)ws; ws += (long)D * D * 2;
    u16* wkt = (u16*)ws; ws += (long)D * D * 2;
    u16* wvt = (u16*)ws; ws += (long)D * D * 2;
    u16* Q   = (u16*)ws; ws += (long)MS * D * 2;
    u16* Km  = (u16*)ws; ws += (long)MS * D * 2;
    u16* VT  = (u16*)ws; ws += (long)D * MS * 2;
    u16* sc  = (u16*)ws; ws += (long)B * S * S * 2;

    const float SCALE = 0.03125f;  // 1/sqrt(1024)

    // 1) convert x -> bf16
    convert_bf16_kernel<<<(int)((MS * D / 4 + 255) / 256), 256, 0, stream>>>(x, xb, (int)(MS * D / 4));
    // 2) transpose weights to [N,K] bf16
    dim3 tb(32, 8);
    transpose_to_bf16_kernel<<<dim3(32, 32), tb, 0, stream>>>(Wq, wqt, D);
    transpose_to_bf16_kernel<<<dim3(32, 32), tb, 0, stream>>>(Wk, wkt, D);
    transpose_to_bf16_kernel<<<dim3(32, 32), tb, 0, stream>>>(Wv, wvt, D);

    // 3) Q = xb @ WqT^T + bq ; K = xb @ WkT^T + bk   ([8192,1024] bf16)
    gemm_bt_kernel<<<dim3(D / 128, MS / 128, 1), 256, 0, stream>>>(
        xb, D, 0, wqt, D, 0, Q, D, 0, 1, bq, 1, nullptr, 0, 1.0f, D);
    gemm_bt_kernel<<<dim3(D / 128, MS / 128, 1), 256, 0, stream>>>(
        xb, D, 0, wkt, D, 0, Km, D, 0, 1, bk, 1, nullptr, 0, 1.0f, D);
    // 4) V^T[d, b*S+s] = sum_k WvT[d,k] xb[b*S+s,k] + bv[d]   ([1024, 8192] bf16)
    gemm_bt_kernel<<<dim3((int)(MS / 128), D / 128, 1), 256, 0, stream>>>(
        wvt, D, 0, xb, D, 0, VT, (int)MS, 0, 1, bv, 2, nullptr, 0, 1.0f, D);

    // 5) scores[b,q,k] = (Q.K^T)*scale + mask  -> bf16, batched over z
    gemm_bt_kernel<<<dim3(S / 128, S / 128, B), 256, 0, stream>>>(
        Q, D, (long)S * D, Km, D, (long)S * D, sc, S, (long)S * S, 1,
        nullptr, 0, mask, S, SCALE, D);

    // 6) softmax in place over last dim
    softmax_kernel<<<B * S, 256, 0, stream>>>(sc);

    // 7) out[b,q,d] = sum_k attn[b,q,k] * VT[d, b*S+k]  (fp32 out)
    gemm_bt_kernel<<<dim3(D / 128, S / 128, B), 256, 0, stream>>>(
        sc, S, (long)S * S, VT, (int)MS, (long)S, out, D, (long)S * D, 0,
        nullptr, 0, nullptr, 0, 1.0f, S);
}

// Round 2
// 360.836 us; speedup vs baseline: 1.1015x; 1.1015x over previous
//
#include <hip/hip_runtime.h>

typedef unsigned short u16;
typedef unsigned int u32;

typedef __attribute__((ext_vector_type(8))) short bf16x8;
typedef __attribute__((ext_vector_type(4))) float f32x4;

static __device__ __forceinline__ u16 f2bf(float f) {
    u32 u = __float_as_uint(f);
    u32 r = (u + 0x7FFFu + ((u >> 16) & 1u)) >> 16;
    return (u16)r;
}
static __device__ __forceinline__ float bf2f(u16 h) {
    return __uint_as_float(((u32)h) << 16);
}

// ---------------- fp32 -> bf16 convert (vectorized) ----------------
__global__ __launch_bounds__(256) void convert_bf16_kernel(const float* __restrict__ x,
                                                           u16* __restrict__ y, int n4) {
    int i = blockIdx.x * 256 + threadIdx.x;
    if (i < n4) {
        float4 v = ((const float4*)x)[i];
        ushort4 o;
        o.x = f2bf(v.x); o.y = f2bf(v.y); o.z = f2bf(v.z); o.w = f2bf(v.w);
        ((ushort4*)y)[i] = o;
    }
}

// ---------------- W [K,N] fp32 -> W^T [N,K] bf16 ----------------
__global__ __launch_bounds__(256) void transpose_to_bf16_kernel(const float* __restrict__ W,
                                                                u16* __restrict__ WT, int D) {
    __shared__ float t[32][33];
    int bx = blockIdx.x, by = blockIdx.y;
    int tx = threadIdx.x, ty = threadIdx.y;
#pragma unroll
    for (int i = ty; i < 32; i += 8)
        t[i][tx] = W[(long)(by * 32 + i) * D + bx * 32 + tx];
    __syncthreads();
#pragma unroll
    for (int i = ty; i < 32; i += 8)
        WT[(long)(bx * 32 + i) * D + by * 32 + tx] = f2bf(t[tx][i]);
}

__global__ __launch_bounds__(256) void concat_bias_kernel(const float* __restrict__ a,
                                                          const float* __restrict__ b,
                                                          float* __restrict__ o, int n) {
    int i = blockIdx.x * 256 + threadIdx.x;
    if (i < 2 * n) o[i] = (i < n) ? a[i] : b[i - n];
}

// ---------------- generic bf16 MFMA GEMM: C[m,n] = scale * sum_k A[m,k]*B[n,k] (+bias)(+mask) --------
// Tile 128x128, BK=64. DOUBLE-BUFFERED LDS (2x32 KB): loads for iter t+1 issue
// before compute of iter t, so the compiler's vmcnt(0) barrier-drain overlaps MFMA.
// XOR chunk swizzle (lc^lr on source k-offset) breaks the 16-way ds_read_b128
// bank conflict while keeping global_load_lds's lane-ordered LDS destination legal.
__global__ __launch_bounds__(256, 2) void gemm_bt_kernel(
    const u16* __restrict__ A, int lda, long sA,
    const u16* __restrict__ B, int ldb, long sB,
    void* __restrict__ C, int ldc, long sC, int c_bf16,
    const float* __restrict__ bias, int bias_mode,
    const float* __restrict__ madd, int mask_ld,
    float scale, int K) {
    __shared__ __align__(16) u16 As[2][128 * 64];
    __shared__ __align__(16) u16 Bs[2][128 * 64];
    const int b = blockIdx.z;
    const u16* Ab = A + (long)b * sA;
    const u16* Bb = B + (long)b * sB;
    const int tm = blockIdx.y * 128, tn = blockIdx.x * 128;
    const int tid = threadIdx.x, wave = tid >> 6, lane = tid & 63;
    const int wm = (wave >> 1) * 64, wn = (wave & 1) * 64;
    const int lr = lane >> 3, lc = lane & 7;   // staging: row-in-group, 16B-chunk
    const int scz = ((lc ^ lr) << 3);          // swizzled source k-offset (elements)
    const int fm = lane & 15, fq = lane >> 4;  // fragment: m/n index, quad

    f32x4 acc[4][4];
#pragma unroll
    for (int i = 0; i < 4; i++)
#pragma unroll
        for (int j = 0; j < 4; j++) acc[i][j] = (f32x4){0.f, 0.f, 0.f, 0.f};

    const int T = K >> 6;

    auto stage = [&](int t, int buf) {
#pragma unroll
        for (int i = 0; i < 4; i++) {
            int row = i * 32 + wave * 8;
            const u16* ga = Ab + (long)(tm + row + lr) * lda + (t << 6) + scz;
            const u16* gb = Bb + (long)(tn + row + lr) * ldb + (t << 6) + scz;
            __builtin_amdgcn_global_load_lds((const __attribute__((address_space(1))) void*)ga,
                                             (__attribute__((address_space(3))) void*)&As[buf][row * 64],
                                             16, 0, 0);
            __builtin_amdgcn_global_load_lds((const __attribute__((address_space(1))) void*)gb,
                                             (__attribute__((address_space(3))) void*)&Bs[buf][row * 64],
                                             16, 0, 0);
        }
    };

    stage(0, 0);
    __syncthreads();
    for (int t = 0; t < T; t++) {
        const int cur = t & 1;
        if (t + 1 < T) stage(t + 1, cur ^ 1);
#pragma unroll
        for (int ks = 0; ks < 2; ks++) {
            bf16x8 af[4], bfr[4];
#pragma unroll
            for (int i = 0; i < 4; i++) {
                int row = wm + i * 16 + fm;
                af[i] = *(const bf16x8*)&As[cur][row * 64 + ((((ks << 2) + fq) ^ (fm & 7)) << 3)];
            }
#pragma unroll
            for (int j = 0; j < 4; j++) {
                int row = wn + j * 16 + fm;
                bfr[j] = *(const bf16x8*)&Bs[cur][row * 64 + ((((ks << 2) + fq) ^ (fm & 7)) << 3)];
            }
#pragma unroll
            for (int i = 0; i < 4; i++)
#pragma unroll
                for (int j = 0; j < 4; j++)
                    acc[i][j] = __builtin_amdgcn_mfma_f32_16x16x32_bf16(af[i], bfr[j], acc[i][j], 0, 0, 0);
        }
        if (t + 1 < T) __syncthreads();
    }

#pragma unroll
    for (int i = 0; i < 4; i++) {
#pragma unroll
        for (int j = 0; j < 4; j++) {
#pragma unroll
            for (int r = 0; r < 4; r++) {
                int row = tm + wm + i * 16 + fq * 4 + r;
                int col = tn + wn + j * 16 + fm;
                float v = acc[i][j][r] * scale;
                if (bias_mode == 1) v += bias[col];
                else if (bias_mode == 2) v += bias[row];
                if (madd) v += madd[(long)row * mask_ld + col];
                if (c_bf16)
                    ((u16*)C)[(long)b * sC + (long)row * ldc + col] = f2bf(v);
                else
                    ((float*)C)[(long)b * sC + (long)row * ldc + col] = v;
            }
        }
    }
}

// ---------------- in-place row softmax over 2048 bf16 cols ----------------
__global__ __launch_bounds__(256) void softmax_kernel(u16* __restrict__ s) {
    const long row = blockIdx.x;
    u16* p = s + row * 2048;
    const int tid = threadIdx.x;
    const int lane = tid & 63, wave = tid >> 6;
    __shared__ float redm[4], reds[4];

    uint4 raw = ((const uint4*)p)[tid];
    float v[8];
    v[0] = bf2f(raw.x & 0xffff); v[1] = bf2f(raw.x >> 16);
    v[2] = bf2f(raw.y & 0xffff); v[3] = bf2f(raw.y >> 16);
    v[4] = bf2f(raw.z & 0xffff); v[5] = bf2f(raw.z >> 16);
    v[6] = bf2f(raw.w & 0xffff); v[7] = bf2f(raw.w >> 16);

    float m = v[0];
#pragma unroll
    for (int k = 1; k < 8; k++) m = fmaxf(m, v[k]);
#pragma unroll
    for (int off = 32; off; off >>= 1) m = fmaxf(m, __shfl_xor(m, off));
    if (lane == 0) redm[wave] = m;
    __syncthreads();
    m = fmaxf(fmaxf(redm[0], redm[1]), fmaxf(redm[2], redm[3]));

    float sum = 0.f;
#pragma unroll
    for (int k = 0; k < 8; k++) { v[k] = __expf(v[k] - m); sum += v[k]; }
#pragma unroll
    for (int off = 32; off; off >>= 1) sum += __shfl_xor(sum, off);
    if (lane == 0) reds[wave] = sum;
    __syncthreads();
    sum = reds[0] + reds[1] + reds[2] + reds[3];
    float inv = 1.f / sum;

    uint4 o;
    o.x = (u32)f2bf(v[0] * inv) | ((u32)f2bf(v[1] * inv) << 16);
    o.y = (u32)f2bf(v[2] * inv) | ((u32)f2bf(v[3] * inv) << 16);
    o.z = (u32)f2bf(v[4] * inv) | ((u32)f2bf(v[5] * inv) << 16);
    o.w = (u32)f2bf(v[6] * inv) | ((u32)f2bf(v[7] * inv) << 16);
    ((uint4*)p)[tid] = o;
}

extern "C" void kernel_launch(void* const* d_in, const int* in_sizes, int n_in,
                              void* d_out, int out_size, void* d_ws, size_t ws_size,
                              hipStream_t stream) {
    const float* x    = (const float*)d_in[0];
    const float* mask = (const float*)d_in[1];
    const float* Wq   = (const float*)d_in[2];
    const float* bq   = (const float*)d_in[3];
    const float* Wk   = (const float*)d_in[4];
    const float* bk   = (const float*)d_in[5];
    const float* Wv   = (const float*)d_in[6];
    const float* bv   = (const float*)d_in[7];
    float* out = (float*)d_out;

    const int B = 4, S = 2048, D = 1024;
    const long MS = (long)B * S;  // 8192

    size_t need = (size_t)MS * D * 2          /* xb */
                + (size_t)(2 * D) * D * 2     /* wqkt */
                + (size_t)D * D * 2           /* wvt */
                + (size_t)(2 * D) * 4         /* bqk */
                + (size_t)MS * (2 * D) * 2    /* QK */
                + (size_t)D * MS * 2          /* VT */
                + (size_t)B * S * S * 2;      /* scores */
    if (ws_size < need) return;

    char* ws = (char*)d_ws;
    u16*  xb   = (u16*)ws;  ws += (long)MS * D * 2;
    u16*  wqkt = (u16*)ws;  ws += (long)(2 * D) * D * 2;
    u16*  wvt  = (u16*)ws;  ws += (long)D * D * 2;
    float* bqk = (float*)ws; ws += (long)(2 * D) * 4;
    u16*  QK   = (u16*)ws;  ws += (long)MS * (2 * D) * 2;
    u16*  VT   = (u16*)ws;  ws += (long)D * MS * 2;
    u16*  sc   = (u16*)ws;  ws += (long)B * S * S * 2;

    const float SCALE = 0.03125f;  // 1/sqrt(1024)

    // 1) convert x -> bf16
    convert_bf16_kernel<<<(int)((MS * D / 4 + 255) / 256), 256, 0, stream>>>(x, xb, (int)(MS * D / 4));
    // 2) transposed bf16 weights: wqkt rows [0,1024)=Wq^T, [1024,2048)=Wk^T; wvt=Wv^T
    dim3 tb(32, 8);
    transpose_to_bf16_kernel<<<dim3(32, 32), tb, 0, stream>>>(Wq, wqkt, D);
    transpose_to_bf16_kernel<<<dim3(32, 32), tb, 0, stream>>>(Wk, wqkt + (long)D * D, D);
    transpose_to_bf16_kernel<<<dim3(32, 32), tb, 0, stream>>>(Wv, wvt, D);
    concat_bias_kernel<<<8, 256, 0, stream>>>(bq, bk, bqk, D);

    // 3) fused QK projection: QK[m, 0:1024]=Q, QK[m, 1024:2048]=K   ([8192, 2048] bf16)
    gemm_bt_kernel<<<dim3(2 * D / 128, (int)(MS / 128), 1), 256, 0, stream>>>(
        xb, D, 0, wqkt, D, 0, QK, 2 * D, 0, 1, bqk, 1, nullptr, 0, 1.0f, D);
    // 4) V^T[d, b*S+s] = sum_k WvT[d,k] xb[b*S+s,k] + bv[d]   ([1024, 8192] bf16)
    gemm_bt_kernel<<<dim3((int)(MS / 128), D / 128, 1), 256, 0, stream>>>(
        wvt, D, 0, xb, D, 0, VT, (int)MS, 0, 1, bv, 2, nullptr, 0, 1.0f, D);

    // 5) scores[b,q,k] = (Q.K^T)*scale + mask  -> bf16, batched over z
    gemm_bt_kernel<<<dim3(S / 128, S / 128, B), 256, 0, stream>>>(
        QK, 2 * D, (long)S * 2 * D, QK + D, 2 * D, (long)S * 2 * D, sc, S, (long)S * S, 1,
        nullptr, 0, mask, S, SCALE, D);

    // 6) softmax in place over last dim
    softmax_kernel<<<B * S, 256, 0, stream>>>(sc);

    // 7) out[b,q,d] = sum_k attn[b,q,k] * VT[d, b*S+k]  (fp32 out)
    gemm_bt_kernel<<<dim3(D / 128, S / 128, B), 256, 0, stream>>>(
        sc, S, (long)S * S, VT, (int)MS, (long)S, out, D, (long)S * D, 0,
        nullptr, 0, nullptr, 0, 1.0f, S);
}